// Round 11
// baseline (218.201 us; speedup 1.0000x reference)
//
#include <hip/hip_runtime.h>

#define NN 100000
#define NE 1600000
#define DD 64

#define NPB 128                        // nodes per bucket
#define NBUCK ((NN + NPB - 1) / NPB)   // 782
#define CAP 3072                       // record capacity per bucket (mean 2046, sigma 45)
#define OVF_CAP 4096
#define CHUNK 4096                     // edges per partition block (r7-proven)
#define NPART ((NE + CHUNK - 1) / CHUNK)  // 391
#define PTHREADS 512                   // partition block size: 8 waves -> ~3 waves/SIMD

// ---------------- primary path ----------------
// ws layout (ints): gcur[NBUCK] (zeroed) | ovf_cnt (zeroed) | pad | ovf[2*OVF_CAP] | sorted[NBUCK*CAP]

// Pass A: partition edges into 782 buckets of 128 nodes (bucket = dst>>7).
// LDS hist -> one global atomicAdd per (block,bucket) reserving rank range ->
// contiguous-rank scatter of 4B packed records (src<<7)|(dst&127).
// 512 threads/block: same 4096-edge chunk as r7 (same atomic count + burst
// length) but 2x the waves to hide the LDS-atomic->store latency chains.
__global__ void __launch_bounds__(PTHREADS) partition3_kernel(
    const int* __restrict__ src, const int* __restrict__ dst,
    int* __restrict__ gcur, int* __restrict__ ovf_cnt, int* __restrict__ ovf,
    unsigned int* __restrict__ sorted) {
  __shared__ int hist[NBUCK];
  __shared__ int base[NBUCK];
  int tid = threadIdx.x;
  int chunk = blockIdx.x * CHUNK;

  for (int i = tid; i < NBUCK; i += PTHREADS) hist[i] = 0;
  __syncthreads();

#pragma unroll
  for (int i = 0; i < CHUNK / PTHREADS; ++i) {
    int e = chunk + i * PTHREADS + tid;
    if (e < NE) atomicAdd(&hist[dst[e] >> 7], 1);
  }
  __syncthreads();

  for (int i = tid; i < NBUCK; i += PTHREADS) {
    int h = hist[i];
    base[i] = h ? atomicAdd(&gcur[i], h) : 0;  // rank start for this block
  }
  __syncthreads();

#pragma unroll
  for (int i = 0; i < CHUNK / PTHREADS; ++i) {
    int e = chunk + i * PTHREADS + tid;
    if (e < NE) {
      int s = src[e], d = dst[e];
      int bk = d >> 7;
      int r = atomicAdd(&base[bk], 1);  // rank within bucket
      if (r < CAP) {
        sorted[bk * CAP + r] = ((unsigned int)s << 7) | (unsigned int)(d & 127);
      } else {
        int oi = atomicAdd(ovf_cnt, 1);
        if (oi < OVF_CAP) { ovf[2 * oi] = s; ovf[2 * oi + 1] = d; }
      }
    }
  }
}

// Pass B (round-7 proven shape): one block per bucket. Build local CSR in LDS
// (int hist + scan + scatter of src ids), then pull4-style gather: quarter-wave
// per node, 4 independent float4 gathers in flight, register accumulation,
// fused (1+eps)*self, coalesced float4 store of rst into out.
// bk0: bucket offset (grid split in halves for profiler visibility).
__global__ void __launch_bounds__(256) bucket_agg2_kernel(
    const float* __restrict__ feat, const float* __restrict__ eps,
    const int* __restrict__ gcur, const unsigned int* __restrict__ sorted,
    float* __restrict__ out, int bk0) {
  __shared__ int lhist[NPB];
  __shared__ int loffs[NPB];   // inclusive scan
  __shared__ int lcur[NPB];
  __shared__ int srcs[CAP];    // 12 KB: src ids grouped by local node
  int tid = threadIdx.x;
  int bk = bk0 + blockIdx.x;
  if (bk >= NBUCK) return;
  int base = bk * CAP;
  int cnt = gcur[bk];
  if (cnt > CAP) cnt = CAP;
  const float4* f4 = reinterpret_cast<const float4*>(feat);

  if (tid < NPB) lhist[tid] = 0;
  __syncthreads();

  // local histogram over 128 node slots (int LDS atomics)
  for (int i = tid; i < cnt; i += 256)
    atomicAdd(&lhist[sorted[base + i] & 127], 1);
  __syncthreads();

  // inclusive Hillis-Steele scan of 128 counters
  if (tid < NPB) loffs[tid] = lhist[tid];
  __syncthreads();
  for (int off = 1; off < NPB; off <<= 1) {
    int t = 0;
    if (tid < NPB && tid >= off) t = loffs[tid - off];
    __syncthreads();
    if (tid < NPB) loffs[tid] += t;
    __syncthreads();
  }
  if (tid < NPB) lcur[tid] = loffs[tid] - lhist[tid];  // exclusive start
  __syncthreads();

  // scatter src ids into per-node-grouped LDS order
  for (int i = tid; i < cnt; i += 256) {
    unsigned int rec = sorted[base + i];
    int pos = atomicAdd(&lcur[rec & 127], 1);
    srcs[pos] = (int)(rec >> 7);
  }
  __syncthreads();

  // pull: quarter-wave per local node, 4-deep gather MLP
  float ec = 1.0f + eps[0];
  int grp = tid >> 4, q = tid & 15;
  int node0 = bk * NPB;
  for (int ln = grp; ln < NPB; ln += 16) {
    int row = node0 + ln;
    if (row >= NN) break;  // rows monotonic per group; only last bucket partial
    int s = loffs[ln] - lhist[ln];
    int e2 = loffs[ln];
    float4 sf = f4[(size_t)row * 16 + q];
    float ax = ec * sf.x, ay = ec * sf.y, az = ec * sf.z, aw = ec * sf.w;
    int k = s;
    for (; k + 4 <= e2; k += 4) {
      int s0 = srcs[k + 0], s1 = srcs[k + 1], s2 = srcs[k + 2], s3 = srcs[k + 3];
      float4 v0 = f4[(size_t)s0 * 16 + q];
      float4 v1 = f4[(size_t)s1 * 16 + q];
      float4 v2 = f4[(size_t)s2 * 16 + q];
      float4 v3 = f4[(size_t)s3 * 16 + q];
      ax += (v0.x + v1.x) + (v2.x + v3.x);
      ay += (v0.y + v1.y) + (v2.y + v3.y);
      az += (v0.z + v1.z) + (v2.z + v3.z);
      aw += (v0.w + v1.w) + (v2.w + v3.w);
    }
    for (; k < e2; ++k) {
      int s4i = srcs[k];
      float4 v = f4[(size_t)s4i * 16 + q];
      ax += v.x; ay += v.y; az += v.z; aw += v.w;
    }
    reinterpret_cast<float4*>(out)[(size_t)row * 16 + q] =
        make_float4(ax, ay, az, aw);
  }
}

// in-place row GEMM v5: gemm3's proven 16-rows/wave shape + overflow-merge
// prologue (expected 0 entries -> one scalar load + skip). Lane = output
// column, W column in VGPRs, rst broadcast via readlane -> fma. Spill-proof.
__global__ void __launch_bounds__(256) row_gemm5_kernel(
    float* __restrict__ out, const float* __restrict__ W,
    const float* __restrict__ b, const int* __restrict__ ovf_cnt,
    const int* __restrict__ ovf, const float* __restrict__ feat) {
  int lane = threadIdx.x & 63;
  int wid  = threadIdx.x >> 6;
  int g = blockIdx.x * 4 + wid;
  if (g >= NN / 16) return;  // wave-uniform guard (6250 full waves)
  int row0 = g * 16;

  float w[64];
#pragma unroll
  for (int k = 0; k < 64; ++k) w[k] = W[k * DD + lane];
  float bv = b[lane];

  int novf = ovf_cnt[0];
  if (novf > OVF_CAP) novf = OVF_CAP;

#pragma unroll
  for (int batch = 0; batch < 2; ++batch) {
    int rbase = row0 + batch * 8;
    float rstv[8], acc[8];
#pragma unroll
    for (int r = 0; r < 8; ++r) rstv[r] = out[(size_t)(rbase + r) * DD + lane];

    if (novf > 0) {  // fold in overflow entries (0 in practice)
      for (int i = 0; i < novf; ++i) {
        int d = ovf[2 * i + 1];
        int r = d - rbase;
        if (r >= 0 && r < 8) rstv[r] += feat[(size_t)ovf[2 * i] * DD + lane];
      }
    }

#pragma unroll
    for (int r = 0; r < 8; ++r) acc[r] = bv;
#pragma unroll
    for (int k = 0; k < 64; ++k) {
#pragma unroll
      for (int r = 0; r < 8; ++r) {
        float s = __uint_as_float(__builtin_amdgcn_readlane(__float_as_uint(rstv[r]), k));
        acc[r] = fmaf(s, w[k], acc[r]);
      }
    }
#pragma unroll
    for (int r = 0; r < 8; ++r) out[(size_t)(rbase + r) * DD + lane] = acc[r];
  }
}

// row GEMM v3 (fallback paths only)
__global__ void __launch_bounds__(256) row_gemm3_kernel(float* __restrict__ out,
                                                        const float* __restrict__ W,
                                                        const float* __restrict__ b) {
  int lane = threadIdx.x & 63;
  int wid  = threadIdx.x >> 6;
  int g = blockIdx.x * 4 + wid;
  if (g >= NN / 16) return;
  int row0 = g * 16;

  float w[64];
#pragma unroll
  for (int k = 0; k < 64; ++k) w[k] = W[k * DD + lane];
  float bv = b[lane];

#pragma unroll
  for (int batch = 0; batch < 2; ++batch) {
    int rbase = row0 + batch * 8;
    float rstv[8], acc[8];
#pragma unroll
    for (int r = 0; r < 8; ++r) rstv[r] = out[(size_t)(rbase + r) * DD + lane];
#pragma unroll
    for (int r = 0; r < 8; ++r) acc[r] = bv;
#pragma unroll
    for (int k = 0; k < 64; ++k) {
#pragma unroll
      for (int r = 0; r < 8; ++r) {
        float s = __uint_as_float(__builtin_amdgcn_readlane(__float_as_uint(rstv[r]), k));
        acc[r] = fmaf(s, w[k], acc[r]);
      }
    }
#pragma unroll
    for (int r = 0; r < 8; ++r) out[(size_t)(rbase + r) * DD + lane] = acc[r];
  }
}

// ---------------- fallback path B: CSR pipeline ----------------

constexpr int NB_SCAN = (NN + 1023) / 1024;

__global__ void __launch_bounds__(256) zero_kernel(int* __restrict__ p, int n) {
  int i = blockIdx.x * blockDim.x + threadIdx.x;
  if (i < n) p[i] = 0;
}

__global__ void __launch_bounds__(256) hist_kernel(const int* __restrict__ dst,
                                                   int* __restrict__ count) {
  int e = blockIdx.x * blockDim.x + threadIdx.x;
  atomicAdd(&count[dst[e]], 1);
}

__global__ void __launch_bounds__(1024) scan1_kernel(const int* __restrict__ count,
                                                     int* __restrict__ offsets,
                                                     int* __restrict__ bsums) {
  __shared__ int tmp[1024];
  int tid = threadIdx.x;
  int gid = blockIdx.x * 1024 + tid;
  int v = (gid < NN) ? count[gid] : 0;
  tmp[tid] = v;
  __syncthreads();
  for (int off = 1; off < 1024; off <<= 1) {
    int t = (tid >= off) ? tmp[tid - off] : 0;
    __syncthreads();
    tmp[tid] += t;
    __syncthreads();
  }
  if (gid < NN) offsets[gid] = tmp[tid] - v;
  if (tid == 1023) bsums[blockIdx.x] = tmp[1023];
}

__global__ void __launch_bounds__(128) scan2_kernel(int* __restrict__ bsums) {
  __shared__ int tmp[128];
  int tid = threadIdx.x;
  int v = (tid < NB_SCAN) ? bsums[tid] : 0;
  tmp[tid] = v;
  __syncthreads();
  for (int off = 1; off < 128; off <<= 1) {
    int t = (tid >= off) ? tmp[tid - off] : 0;
    __syncthreads();
    tmp[tid] += t;
    __syncthreads();
  }
  if (tid < NB_SCAN) bsums[tid] = tmp[tid] - v;
}

__global__ void __launch_bounds__(256) scan3_kernel(int* __restrict__ offsets,
                                                    const int* __restrict__ bsums,
                                                    int* __restrict__ cursor) {
  int gid = blockIdx.x * blockDim.x + threadIdx.x;
  if (gid < NN) {
    int o = offsets[gid] + bsums[gid >> 10];
    offsets[gid] = o;
    cursor[gid] = o;
  } else if (gid == NN) {
    offsets[NN] = NE;
  }
}

__global__ void __launch_bounds__(256) place_kernel(const int* __restrict__ src,
                                                    const int* __restrict__ dst,
                                                    int* __restrict__ cursor,
                                                    int* __restrict__ sorted) {
  int e = blockIdx.x * blockDim.x + threadIdx.x;
  int p = atomicAdd(&cursor[dst[e]], 1);
  sorted[p] = src[e];
}

__global__ void __launch_bounds__(256) pull4_kernel(const float* __restrict__ feat,
                                                    const float* __restrict__ eps,
                                                    const int* __restrict__ offsets,
                                                    const int* __restrict__ sorted,
                                                    float* __restrict__ out) {
  int t = blockIdx.x * blockDim.x + threadIdx.x;
  int node = t >> 4;
  int q = t & 15;
  const float4* f4 = reinterpret_cast<const float4*>(feat);

  int start = offsets[node];
  int end   = offsets[node + 1];
  float e = 1.0f + eps[0];
  float4 self = f4[(size_t)node * 16 + q];
  float ax = e * self.x, ay = e * self.y, az = e * self.z, aw = e * self.w;

  int k = start;
  for (; k + 4 <= end; k += 4) {
    int s0 = sorted[k + 0], s1 = sorted[k + 1], s2 = sorted[k + 2], s3 = sorted[k + 3];
    float4 v0 = f4[(size_t)s0 * 16 + q];
    float4 v1 = f4[(size_t)s1 * 16 + q];
    float4 v2 = f4[(size_t)s2 * 16 + q];
    float4 v3 = f4[(size_t)s3 * 16 + q];
    ax += (v0.x + v1.x) + (v2.x + v3.x);
    ay += (v0.y + v1.y) + (v2.y + v3.y);
    az += (v0.z + v1.z) + (v2.z + v3.z);
    aw += (v0.w + v1.w) + (v2.w + v3.w);
  }
  for (; k < end; ++k) {
    int s = sorted[k];
    float4 v = f4[(size_t)s * 16 + q];
    ax += v.x; ay += v.y; az += v.z; aw += v.w;
  }

  reinterpret_cast<float4*>(out)[(size_t)node * 16 + q] = make_float4(ax, ay, az, aw);
}

// ---------------- fallback path C: atomic scatter ----------------

__global__ void __launch_bounds__(256) init_out_kernel(const float* __restrict__ feat,
                                                       const float* __restrict__ eps,
                                                       float* __restrict__ out) {
  int i = blockIdx.x * blockDim.x + threadIdx.x;
  float e = 1.0f + eps[0];
  float4 f = reinterpret_cast<const float4*>(feat)[i];
  reinterpret_cast<float4*>(out)[i] = make_float4(e * f.x, e * f.y, e * f.z, e * f.w);
}

__global__ void __launch_bounds__(256) scatter_edges_kernel(const float* __restrict__ feat,
                                                            const int* __restrict__ src,
                                                            const int* __restrict__ dst,
                                                            float* __restrict__ out) {
  int t = blockIdx.x * blockDim.x + threadIdx.x;
  int e = t >> 4;
  int q = t & 15;
  int s = src[e];
  int d = dst[e];
  float4 v = reinterpret_cast<const float4*>(feat)[s * 16 + q];
  float* op = out + d * DD + q * 4;
  atomicAdd(op + 0, v.x);
  atomicAdd(op + 1, v.y);
  atomicAdd(op + 2, v.z);
  atomicAdd(op + 3, v.w);
}

// ---------------- launch ----------------

extern "C" void kernel_launch(void* const* d_in, const int* in_sizes, int n_in,
                              void* d_out, int out_size, void* d_ws, size_t ws_size,
                              hipStream_t stream) {
  const float* feat = (const float*)d_in[0];
  const int* src    = (const int*)d_in[1];
  const int* dst    = (const int*)d_in[2];
  const float* eps  = (const float*)d_in[3];
  const float* W    = (const float*)d_in[4];
  const float* b    = (const float*)d_in[5];
  float* out        = (float*)d_out;

  // primary ws layout (ints): gcur[NBUCK] | ovf_cnt | pad | ovf[2*OVF_CAP] | sorted[NBUCK*CAP]
  const size_t needA = ((size_t)NBUCK + 2 + 2 * OVF_CAP + (size_t)NBUCK * CAP) * sizeof(int);
  // fallback B layout (ints): count[NN] | offsets[NN+1 pad 8] | cursor[NN] | bsums[128] | sorted[NE]
  const size_t needB = ((size_t)3 * NN + 136 + NE) * sizeof(int);

  if (ws_size >= needA) {
    int* wsI = (int*)d_ws;
    int* gcur    = wsI;
    int* ovf_cnt = wsI + NBUCK;
    int* ovf     = wsI + NBUCK + 2;
    unsigned int* sorted = (unsigned int*)(wsI + NBUCK + 2 + 2 * OVF_CAP);

    hipMemsetAsync(gcur, 0, (NBUCK + 2) * sizeof(int), stream);
    partition3_kernel<<<NPART, PTHREADS, 0, stream>>>(src, dst, gcur, ovf_cnt, ovf, sorted);
    // agg grid split in two halves: exposes the next-biggest kernel in top-5
    const int half = (NBUCK + 1) / 2;  // 391
    bucket_agg2_kernel<<<half, 256, 0, stream>>>(feat, eps, gcur, sorted, out, 0);
    bucket_agg2_kernel<<<NBUCK - half, 256, 0, stream>>>(feat, eps, gcur, sorted, out, half);
    row_gemm5_kernel<<<(NN / 16 + 3) / 4, 256, 0, stream>>>(out, W, b, ovf_cnt, ovf, feat);
  } else if (ws_size >= needB) {
    int* wsI     = (int*)d_ws;
    int* count   = wsI;
    int* offsets = wsI + NN;
    int* cursor  = wsI + 2 * NN + 8;
    int* bsums   = wsI + 3 * NN + 8;
    int* sortedB = wsI + 3 * NN + 136;

    zero_kernel<<<(NN + 255) / 256, 256, 0, stream>>>(count, NN);
    hist_kernel<<<NE / 256, 256, 0, stream>>>(dst, count);
    scan1_kernel<<<NB_SCAN, 1024, 0, stream>>>(count, offsets, bsums);
    scan2_kernel<<<1, 128, 0, stream>>>(bsums);
    scan3_kernel<<<(NN + 1 + 255) / 256, 256, 0, stream>>>(offsets, bsums, cursor);
    place_kernel<<<NE / 256, 256, 0, stream>>>(src, dst, cursor, sortedB);
    pull4_kernel<<<(NN * 16) / 256, 256, 0, stream>>>(feat, eps, offsets, sortedB, out);
    row_gemm3_kernel<<<(NN / 16 + 3) / 4, 256, 0, stream>>>(out, W, b);
  } else {
    init_out_kernel<<<(NN * DD / 4) / 256, 256, 0, stream>>>(feat, eps, out);
    scatter_edges_kernel<<<(NE * 16) / 256, 256, 0, stream>>>(feat, src, dst, out);
    row_gemm3_kernel<<<(NN / 16 + 3) / 4, 256, 0, stream>>>(out, W, b);
  }
}

// Round 12
// 202.658 us; speedup vs baseline: 1.0767x; 1.0767x over previous
//
#include <hip/hip_runtime.h>

#define NN 100000
#define NE 1600000
#define DD 64

#define NPB 128                        // nodes per bucket
#define NBUCK ((NN + NPB - 1) / NPB)   // 782
#define CAP 3072                       // record capacity per bucket (mean 2046, sigma 45)
#define OVF_CAP 4096
#define CHUNK 16384                    // edges per partition block (84B dest runs)
#define NPART ((NE + CHUNK - 1) / CHUNK)  // 98
#define PTHREADS 1024                  // 16 waves/block -> ~6 waves/CU at 98 blocks

// ---------------- primary path ----------------
// ws layout (ints): gcur[NBUCK] (zeroed) | ovf_cnt (zeroed) | pad | ovf[2*OVF_CAP] | sorted[NBUCK*CAP]

// Pass A: partition edges into 782 buckets of 128 nodes (bucket = dst>>7).
// LDS hist -> one global atomicAdd per (block,bucket) reserving rank range ->
// contiguous-rank scatter of 4B packed records (src<<7)|(dst&127).
// CHUNK=16384: ~21 records per (block,bucket) = 84B dest runs (low line-amp);
// 1024 threads: 16 waves of TLP for the LDS-atomic->scattered-store chains.
__global__ void __launch_bounds__(PTHREADS) partition4_kernel(
    const int* __restrict__ src, const int* __restrict__ dst,
    int* __restrict__ gcur, int* __restrict__ ovf_cnt, int* __restrict__ ovf,
    unsigned int* __restrict__ sorted) {
  __shared__ int hist[NBUCK];
  __shared__ int base[NBUCK];
  int tid = threadIdx.x;
  int chunk = blockIdx.x * CHUNK;

  for (int i = tid; i < NBUCK; i += PTHREADS) hist[i] = 0;
  __syncthreads();

#pragma unroll
  for (int i = 0; i < CHUNK / PTHREADS; ++i) {
    int e = chunk + i * PTHREADS + tid;
    if (e < NE) atomicAdd(&hist[dst[e] >> 7], 1);
  }
  __syncthreads();

  for (int i = tid; i < NBUCK; i += PTHREADS) {
    int h = hist[i];
    base[i] = h ? atomicAdd(&gcur[i], h) : 0;  // rank start for this block
  }
  __syncthreads();

#pragma unroll
  for (int i = 0; i < CHUNK / PTHREADS; ++i) {
    int e = chunk + i * PTHREADS + tid;
    if (e < NE) {
      int s = src[e], d = dst[e];
      int bk = d >> 7;
      int r = atomicAdd(&base[bk], 1);  // rank within bucket
      if (r < CAP) {
        sorted[bk * CAP + r] = ((unsigned int)s << 7) | (unsigned int)(d & 127);
      } else {
        int oi = atomicAdd(ovf_cnt, 1);
        if (oi < OVF_CAP) { ovf[2 * oi] = s; ovf[2 * oi + 1] = d; }
      }
    }
  }
}

// Pass B (round-7 proven shape, single 782-block dispatch — splitting measured
// +23us, r11): one block per bucket. Build local CSR in LDS (int hist + scan +
// scatter of src ids), then pull4-style gather: quarter-wave per node, 4
// independent float4 gathers in flight, register accumulation, fused
// (1+eps)*self, coalesced float4 store of rst into out.
// At the gather roofline: 410MB intrinsic volume at ~6.3TB/s effective (r7-r11).
__global__ void __launch_bounds__(256) bucket_agg2_kernel(
    const float* __restrict__ feat, const float* __restrict__ eps,
    const int* __restrict__ gcur, const unsigned int* __restrict__ sorted,
    float* __restrict__ out) {
  __shared__ int lhist[NPB];
  __shared__ int loffs[NPB];   // inclusive scan
  __shared__ int lcur[NPB];
  __shared__ int srcs[CAP];    // 12 KB: src ids grouped by local node
  int tid = threadIdx.x;
  int bk = blockIdx.x;
  int base = bk * CAP;
  int cnt = gcur[bk];
  if (cnt > CAP) cnt = CAP;
  const float4* f4 = reinterpret_cast<const float4*>(feat);

  if (tid < NPB) lhist[tid] = 0;
  __syncthreads();

  // local histogram over 128 node slots (int LDS atomics)
  for (int i = tid; i < cnt; i += 256)
    atomicAdd(&lhist[sorted[base + i] & 127], 1);
  __syncthreads();

  // inclusive Hillis-Steele scan of 128 counters
  if (tid < NPB) loffs[tid] = lhist[tid];
  __syncthreads();
  for (int off = 1; off < NPB; off <<= 1) {
    int t = 0;
    if (tid < NPB && tid >= off) t = loffs[tid - off];
    __syncthreads();
    if (tid < NPB) loffs[tid] += t;
    __syncthreads();
  }
  if (tid < NPB) lcur[tid] = loffs[tid] - lhist[tid];  // exclusive start
  __syncthreads();

  // scatter src ids into per-node-grouped LDS order
  for (int i = tid; i < cnt; i += 256) {
    unsigned int rec = sorted[base + i];
    int pos = atomicAdd(&lcur[rec & 127], 1);
    srcs[pos] = (int)(rec >> 7);
  }
  __syncthreads();

  // pull: quarter-wave per local node, 4-deep gather MLP
  float ec = 1.0f + eps[0];
  int grp = tid >> 4, q = tid & 15;
  int node0 = bk * NPB;
  for (int ln = grp; ln < NPB; ln += 16) {
    int row = node0 + ln;
    if (row >= NN) break;  // rows monotonic per group; only last bucket partial
    int s = loffs[ln] - lhist[ln];
    int e2 = loffs[ln];
    float4 sf = f4[(size_t)row * 16 + q];
    float ax = ec * sf.x, ay = ec * sf.y, az = ec * sf.z, aw = ec * sf.w;
    int k = s;
    for (; k + 4 <= e2; k += 4) {
      int s0 = srcs[k + 0], s1 = srcs[k + 1], s2 = srcs[k + 2], s3 = srcs[k + 3];
      float4 v0 = f4[(size_t)s0 * 16 + q];
      float4 v1 = f4[(size_t)s1 * 16 + q];
      float4 v2 = f4[(size_t)s2 * 16 + q];
      float4 v3 = f4[(size_t)s3 * 16 + q];
      ax += (v0.x + v1.x) + (v2.x + v3.x);
      ay += (v0.y + v1.y) + (v2.y + v3.y);
      az += (v0.z + v1.z) + (v2.z + v3.z);
      aw += (v0.w + v1.w) + (v2.w + v3.w);
    }
    for (; k < e2; ++k) {
      int s4i = srcs[k];
      float4 v = f4[(size_t)s4i * 16 + q];
      ax += v.x; ay += v.y; az += v.z; aw += v.w;
    }
    reinterpret_cast<float4*>(out)[(size_t)row * 16 + q] =
        make_float4(ax, ay, az, aw);
  }
}

// in-place row GEMM v5: gemm3's proven 16-rows/wave shape + overflow-merge
// prologue (expected 0 entries -> one scalar load + skip). Lane = output
// column, W column in VGPRs, rst broadcast via readlane -> fma. Spill-proof.
__global__ void __launch_bounds__(256) row_gemm5_kernel(
    float* __restrict__ out, const float* __restrict__ W,
    const float* __restrict__ b, const int* __restrict__ ovf_cnt,
    const int* __restrict__ ovf, const float* __restrict__ feat) {
  int lane = threadIdx.x & 63;
  int wid  = threadIdx.x >> 6;
  int g = blockIdx.x * 4 + wid;
  if (g >= NN / 16) return;  // wave-uniform guard (6250 full waves)
  int row0 = g * 16;

  float w[64];
#pragma unroll
  for (int k = 0; k < 64; ++k) w[k] = W[k * DD + lane];
  float bv = b[lane];

  int novf = ovf_cnt[0];
  if (novf > OVF_CAP) novf = OVF_CAP;

#pragma unroll
  for (int batch = 0; batch < 2; ++batch) {
    int rbase = row0 + batch * 8;
    float rstv[8], acc[8];
#pragma unroll
    for (int r = 0; r < 8; ++r) rstv[r] = out[(size_t)(rbase + r) * DD + lane];

    if (novf > 0) {  // fold in overflow entries (0 in practice)
      for (int i = 0; i < novf; ++i) {
        int d = ovf[2 * i + 1];
        int r = d - rbase;
        if (r >= 0 && r < 8) rstv[r] += feat[(size_t)ovf[2 * i] * DD + lane];
      }
    }

#pragma unroll
    for (int r = 0; r < 8; ++r) acc[r] = bv;
#pragma unroll
    for (int k = 0; k < 64; ++k) {
#pragma unroll
      for (int r = 0; r < 8; ++r) {
        float s = __uint_as_float(__builtin_amdgcn_readlane(__float_as_uint(rstv[r]), k));
        acc[r] = fmaf(s, w[k], acc[r]);
      }
    }
#pragma unroll
    for (int r = 0; r < 8; ++r) out[(size_t)(rbase + r) * DD + lane] = acc[r];
  }
}

// row GEMM v3 (fallback paths only)
__global__ void __launch_bounds__(256) row_gemm3_kernel(float* __restrict__ out,
                                                        const float* __restrict__ W,
                                                        const float* __restrict__ b) {
  int lane = threadIdx.x & 63;
  int wid  = threadIdx.x >> 6;
  int g = blockIdx.x * 4 + wid;
  if (g >= NN / 16) return;
  int row0 = g * 16;

  float w[64];
#pragma unroll
  for (int k = 0; k < 64; ++k) w[k] = W[k * DD + lane];
  float bv = b[lane];

#pragma unroll
  for (int batch = 0; batch < 2; ++batch) {
    int rbase = row0 + batch * 8;
    float rstv[8], acc[8];
#pragma unroll
    for (int r = 0; r < 8; ++r) rstv[r] = out[(size_t)(rbase + r) * DD + lane];
#pragma unroll
    for (int r = 0; r < 8; ++r) acc[r] = bv;
#pragma unroll
    for (int k = 0; k < 64; ++k) {
#pragma unroll
      for (int r = 0; r < 8; ++r) {
        float s = __uint_as_float(__builtin_amdgcn_readlane(__float_as_uint(rstv[r]), k));
        acc[r] = fmaf(s, w[k], acc[r]);
      }
    }
#pragma unroll
    for (int r = 0; r < 8; ++r) out[(size_t)(rbase + r) * DD + lane] = acc[r];
  }
}

// ---------------- fallback path B: CSR pipeline ----------------

constexpr int NB_SCAN = (NN + 1023) / 1024;

__global__ void __launch_bounds__(256) zero_kernel(int* __restrict__ p, int n) {
  int i = blockIdx.x * blockDim.x + threadIdx.x;
  if (i < n) p[i] = 0;
}

__global__ void __launch_bounds__(256) hist_kernel(const int* __restrict__ dst,
                                                   int* __restrict__ count) {
  int e = blockIdx.x * blockDim.x + threadIdx.x;
  atomicAdd(&count[dst[e]], 1);
}

__global__ void __launch_bounds__(1024) scan1_kernel(const int* __restrict__ count,
                                                     int* __restrict__ offsets,
                                                     int* __restrict__ bsums) {
  __shared__ int tmp[1024];
  int tid = threadIdx.x;
  int gid = blockIdx.x * 1024 + tid;
  int v = (gid < NN) ? count[gid] : 0;
  tmp[tid] = v;
  __syncthreads();
  for (int off = 1; off < 1024; off <<= 1) {
    int t = (tid >= off) ? tmp[tid - off] : 0;
    __syncthreads();
    tmp[tid] += t;
    __syncthreads();
  }
  if (gid < NN) offsets[gid] = tmp[tid] - v;
  if (tid == 1023) bsums[blockIdx.x] = tmp[1023];
}

__global__ void __launch_bounds__(128) scan2_kernel(int* __restrict__ bsums) {
  __shared__ int tmp[128];
  int tid = threadIdx.x;
  int v = (tid < NB_SCAN) ? bsums[tid] : 0;
  tmp[tid] = v;
  __syncthreads();
  for (int off = 1; off < 128; off <<= 1) {
    int t = (tid >= off) ? tmp[tid - off] : 0;
    __syncthreads();
    tmp[tid] += t;
    __syncthreads();
  }
  if (tid < NB_SCAN) bsums[tid] = tmp[tid] - v;
}

__global__ void __launch_bounds__(256) scan3_kernel(int* __restrict__ offsets,
                                                    const int* __restrict__ bsums,
                                                    int* __restrict__ cursor) {
  int gid = blockIdx.x * blockDim.x + threadIdx.x;
  if (gid < NN) {
    int o = offsets[gid] + bsums[gid >> 10];
    offsets[gid] = o;
    cursor[gid] = o;
  } else if (gid == NN) {
    offsets[NN] = NE;
  }
}

__global__ void __launch_bounds__(256) place_kernel(const int* __restrict__ src,
                                                    const int* __restrict__ dst,
                                                    int* __restrict__ cursor,
                                                    int* __restrict__ sorted) {
  int e = blockIdx.x * blockDim.x + threadIdx.x;
  int p = atomicAdd(&cursor[dst[e]], 1);
  sorted[p] = src[e];
}

__global__ void __launch_bounds__(256) pull4_kernel(const float* __restrict__ feat,
                                                    const float* __restrict__ eps,
                                                    const int* __restrict__ offsets,
                                                    const int* __restrict__ sorted,
                                                    float* __restrict__ out) {
  int t = blockIdx.x * blockDim.x + threadIdx.x;
  int node = t >> 4;
  int q = t & 15;
  const float4* f4 = reinterpret_cast<const float4*>(feat);

  int start = offsets[node];
  int end   = offsets[node + 1];
  float e = 1.0f + eps[0];
  float4 self = f4[(size_t)node * 16 + q];
  float ax = e * self.x, ay = e * self.y, az = e * self.z, aw = e * self.w;

  int k = start;
  for (; k + 4 <= end; k += 4) {
    int s0 = sorted[k + 0], s1 = sorted[k + 1], s2 = sorted[k + 2], s3 = sorted[k + 3];
    float4 v0 = f4[(size_t)s0 * 16 + q];
    float4 v1 = f4[(size_t)s1 * 16 + q];
    float4 v2 = f4[(size_t)s2 * 16 + q];
    float4 v3 = f4[(size_t)s3 * 16 + q];
    ax += (v0.x + v1.x) + (v2.x + v3.x);
    ay += (v0.y + v1.y) + (v2.y + v3.y);
    az += (v0.z + v1.z) + (v2.z + v3.z);
    aw += (v0.w + v1.w) + (v2.w + v3.w);
  }
  for (; k < end; ++k) {
    int s = sorted[k];
    float4 v = f4[(size_t)s * 16 + q];
    ax += v.x; ay += v.y; az += v.z; aw += v.w;
  }

  reinterpret_cast<float4*>(out)[(size_t)node * 16 + q] = make_float4(ax, ay, az, aw);
}

// ---------------- fallback path C: atomic scatter ----------------

__global__ void __launch_bounds__(256) init_out_kernel(const float* __restrict__ feat,
                                                       const float* __restrict__ eps,
                                                       float* __restrict__ out) {
  int i = blockIdx.x * blockDim.x + threadIdx.x;
  float e = 1.0f + eps[0];
  float4 f = reinterpret_cast<const float4*>(feat)[i];
  reinterpret_cast<float4*>(out)[i] = make_float4(e * f.x, e * f.y, e * f.z, e * f.w);
}

__global__ void __launch_bounds__(256) scatter_edges_kernel(const float* __restrict__ feat,
                                                            const int* __restrict__ src,
                                                            const int* __restrict__ dst,
                                                            float* __restrict__ out) {
  int t = blockIdx.x * blockDim.x + threadIdx.x;
  int e = t >> 4;
  int q = t & 15;
  int s = src[e];
  int d = dst[e];
  float4 v = reinterpret_cast<const float4*>(feat)[s * 16 + q];
  float* op = out + d * DD + q * 4;
  atomicAdd(op + 0, v.x);
  atomicAdd(op + 1, v.y);
  atomicAdd(op + 2, v.z);
  atomicAdd(op + 3, v.w);
}

// ---------------- launch ----------------

extern "C" void kernel_launch(void* const* d_in, const int* in_sizes, int n_in,
                              void* d_out, int out_size, void* d_ws, size_t ws_size,
                              hipStream_t stream) {
  const float* feat = (const float*)d_in[0];
  const int* src    = (const int*)d_in[1];
  const int* dst    = (const int*)d_in[2];
  const float* eps  = (const float*)d_in[3];
  const float* W    = (const float*)d_in[4];
  const float* b    = (const float*)d_in[5];
  float* out        = (float*)d_out;

  // primary ws layout (ints): gcur[NBUCK] | ovf_cnt | pad | ovf[2*OVF_CAP] | sorted[NBUCK*CAP]
  const size_t needA = ((size_t)NBUCK + 2 + 2 * OVF_CAP + (size_t)NBUCK * CAP) * sizeof(int);
  // fallback B layout (ints): count[NN] | offsets[NN+1 pad 8] | cursor[NN] | bsums[128] | sorted[NE]
  const size_t needB = ((size_t)3 * NN + 136 + NE) * sizeof(int);

  if (ws_size >= needA) {
    int* wsI = (int*)d_ws;
    int* gcur    = wsI;
    int* ovf_cnt = wsI + NBUCK;
    int* ovf     = wsI + NBUCK + 2;
    unsigned int* sorted = (unsigned int*)(wsI + NBUCK + 2 + 2 * OVF_CAP);

    hipMemsetAsync(gcur, 0, (NBUCK + 2) * sizeof(int), stream);
    partition4_kernel<<<NPART, PTHREADS, 0, stream>>>(src, dst, gcur, ovf_cnt, ovf, sorted);
    bucket_agg2_kernel<<<NBUCK, 256, 0, stream>>>(feat, eps, gcur, sorted, out);
    row_gemm5_kernel<<<(NN / 16 + 3) / 4, 256, 0, stream>>>(out, W, b, ovf_cnt, ovf, feat);
  } else if (ws_size >= needB) {
    int* wsI     = (int*)d_ws;
    int* count   = wsI;
    int* offsets = wsI + NN;
    int* cursor  = wsI + 2 * NN + 8;
    int* bsums   = wsI + 3 * NN + 8;
    int* sortedB = wsI + 3 * NN + 136;

    zero_kernel<<<(NN + 255) / 256, 256, 0, stream>>>(count, NN);
    hist_kernel<<<NE / 256, 256, 0, stream>>>(dst, count);
    scan1_kernel<<<NB_SCAN, 1024, 0, stream>>>(count, offsets, bsums);
    scan2_kernel<<<1, 128, 0, stream>>>(bsums);
    scan3_kernel<<<(NN + 1 + 255) / 256, 256, 0, stream>>>(offsets, bsums, cursor);
    place_kernel<<<NE / 256, 256, 0, stream>>>(src, dst, cursor, sortedB);
    pull4_kernel<<<(NN * 16) / 256, 256, 0, stream>>>(feat, eps, offsets, sortedB, out);
    row_gemm3_kernel<<<(NN / 16 + 3) / 4, 256, 0, stream>>>(out, W, b);
  } else {
    init_out_kernel<<<(NN * DD / 4) / 256, 256, 0, stream>>>(feat, eps, out);
    scatter_edges_kernel<<<(NE * 16) / 256, 256, 0, stream>>>(feat, src, dst, out);
    row_gemm3_kernel<<<(NN / 16 + 3) / 4, 256, 0, stream>>>(out, W, b);
  }
}

// Round 15
// 198.727 us; speedup vs baseline: 1.0980x; 1.0198x over previous
//
#include <hip/hip_runtime.h>

#define NN 100000
#define NE 1600000
#define DD 64

#define NPB 128                        // nodes per bucket
#define NBUCK ((NN + NPB - 1) / NPB)   // 782
#define CAP 3072                       // record capacity per bucket (mean 2046, sigma 45)
#define OVF_CAP 4096
#define CHUNK 4096                     // edges per partition block
#define NPART ((NE + CHUNK - 1) / CHUNK)  // 391 blocks -> all 256 CUs active
#define PTHREADS 1024                  // 16 waves/block, 4 edges/thread

// ---------------- primary path ----------------
// ws layout (ints): gcur[NBUCK] (zeroed) | ovf_cnt (zeroed) | pad | ovf[2*OVF_CAP] | sorted[NBUCK*CAP]

// Pass A: partition edges into 782 buckets of 128 nodes (bucket = dst>>7).
// LDS hist -> one global atomicAdd per (block,bucket) reserving rank range ->
// contiguous-rank scatter of 4B packed records (src<<7)|(dst&127).
// 391 blocks x 16 waves: every CU busy (vs 98 blocks = 38% in r12).
__global__ void __launch_bounds__(PTHREADS) partition5_kernel(
    const int* __restrict__ src, const int* __restrict__ dst,
    int* __restrict__ gcur, int* __restrict__ ovf_cnt, int* __restrict__ ovf,
    unsigned int* __restrict__ sorted) {
  __shared__ int hist[NBUCK];
  __shared__ int base[NBUCK];
  int tid = threadIdx.x;
  int chunk = blockIdx.x * CHUNK;

  for (int i = tid; i < NBUCK; i += PTHREADS) hist[i] = 0;
  __syncthreads();

#pragma unroll
  for (int i = 0; i < CHUNK / PTHREADS; ++i) {
    int e = chunk + i * PTHREADS + tid;
    if (e < NE) atomicAdd(&hist[dst[e] >> 7], 1);
  }
  __syncthreads();

  for (int i = tid; i < NBUCK; i += PTHREADS) {
    int h = hist[i];
    base[i] = h ? atomicAdd(&gcur[i], h) : 0;  // rank start for this block
  }
  __syncthreads();

#pragma unroll
  for (int i = 0; i < CHUNK / PTHREADS; ++i) {
    int e = chunk + i * PTHREADS + tid;
    if (e < NE) {
      int s = src[e], d = dst[e];
      int bk = d >> 7;
      int r = atomicAdd(&base[bk], 1);  // rank within bucket
      if (r < CAP) {
        sorted[bk * CAP + r] = ((unsigned int)s << 7) | (unsigned int)(d & 127);
      } else {
        int oi = atomicAdd(ovf_cnt, 1);
        if (oi < OVF_CAP) { ovf[2 * oi] = s; ovf[2 * oi + 1] = d; }
      }
    }
  }
}

// Pass B (round-7 proven shape, single 782-block dispatch — splitting measured
// +23us, r11): build local CSR in LDS, then pull4-style gather: quarter-wave
// per node, 4 independent float4 gathers in flight, register accumulation,
// fused (1+eps)*self, coalesced float4 store. At the gather roofline (~65us).
__global__ void __launch_bounds__(256) bucket_agg2_kernel(
    const float* __restrict__ feat, const float* __restrict__ eps,
    const int* __restrict__ gcur, const unsigned int* __restrict__ sorted,
    float* __restrict__ out) {
  __shared__ int lhist[NPB];
  __shared__ int loffs[NPB];   // inclusive scan
  __shared__ int lcur[NPB];
  __shared__ int srcs[CAP];    // 12 KB: src ids grouped by local node
  int tid = threadIdx.x;
  int bk = blockIdx.x;
  int base = bk * CAP;
  int cnt = gcur[bk];
  if (cnt > CAP) cnt = CAP;
  const float4* f4 = reinterpret_cast<const float4*>(feat);

  if (tid < NPB) lhist[tid] = 0;
  __syncthreads();

  for (int i = tid; i < cnt; i += 256)
    atomicAdd(&lhist[sorted[base + i] & 127], 1);
  __syncthreads();

  if (tid < NPB) loffs[tid] = lhist[tid];
  __syncthreads();
  for (int off = 1; off < NPB; off <<= 1) {
    int t = 0;
    if (tid < NPB && tid >= off) t = loffs[tid - off];
    __syncthreads();
    if (tid < NPB) loffs[tid] += t;
    __syncthreads();
  }
  if (tid < NPB) lcur[tid] = loffs[tid] - lhist[tid];  // exclusive start
  __syncthreads();

  for (int i = tid; i < cnt; i += 256) {
    unsigned int rec = sorted[base + i];
    int pos = atomicAdd(&lcur[rec & 127], 1);
    srcs[pos] = (int)(rec >> 7);
  }
  __syncthreads();

  float ec = 1.0f + eps[0];
  int grp = tid >> 4, q = tid & 15;
  int node0 = bk * NPB;
  for (int ln = grp; ln < NPB; ln += 16) {
    int row = node0 + ln;
    if (row >= NN) break;
    int s = loffs[ln] - lhist[ln];
    int e2 = loffs[ln];
    float4 sf = f4[(size_t)row * 16 + q];
    float ax = ec * sf.x, ay = ec * sf.y, az = ec * sf.z, aw = ec * sf.w;
    int k = s;
    for (; k + 4 <= e2; k += 4) {
      int s0 = srcs[k + 0], s1 = srcs[k + 1], s2 = srcs[k + 2], s3 = srcs[k + 3];
      float4 v0 = f4[(size_t)s0 * 16 + q];
      float4 v1 = f4[(size_t)s1 * 16 + q];
      float4 v2 = f4[(size_t)s2 * 16 + q];
      float4 v3 = f4[(size_t)s3 * 16 + q];
      ax += (v0.x + v1.x) + (v2.x + v3.x);
      ay += (v0.y + v1.y) + (v2.y + v3.y);
      az += (v0.z + v1.z) + (v2.z + v3.z);
      aw += (v0.w + v1.w) + (v2.w + v3.w);
    }
    for (; k < e2; ++k) {
      int s4i = srcs[k];
      float4 v = f4[(size_t)s4i * 16 + q];
      ax += v.x; ay += v.y; az += v.z; aw += v.w;
    }
    reinterpret_cast<float4*>(out)[(size_t)row * 16 + q] =
        make_float4(ax, ay, az, aw);
  }
}

// in-place row GEMM v6: gemm5 + software-pipelined readlanes. The 8 readlanes
// for step k+1 are issued a full iteration before their consuming fmas, so the
// v_readlane->SGPR results are >=16 cycles old when v_fmac reads them (breaks
// the VALU->VALU SGPR RAW hazard that pairs each readlane with its fma).
__global__ void __launch_bounds__(256) row_gemm6_kernel(
    float* __restrict__ out, const float* __restrict__ W,
    const float* __restrict__ b, const int* __restrict__ ovf_cnt,
    const int* __restrict__ ovf, const float* __restrict__ feat) {
  int lane = threadIdx.x & 63;
  int wid  = threadIdx.x >> 6;
  int g = blockIdx.x * 4 + wid;
  if (g >= NN / 16) return;  // wave-uniform guard (6250 full waves)
  int row0 = g * 16;

  float w[64];
#pragma unroll
  for (int k = 0; k < 64; ++k) w[k] = W[k * DD + lane];
  float bv = b[lane];

  int novf = ovf_cnt[0];
  if (novf > OVF_CAP) novf = OVF_CAP;

#pragma unroll
  for (int batch = 0; batch < 2; ++batch) {
    int rbase = row0 + batch * 8;
    float rstv[8], acc[8];
#pragma unroll
    for (int r = 0; r < 8; ++r) rstv[r] = out[(size_t)(rbase + r) * DD + lane];

    if (novf > 0) {  // fold in overflow entries (0 in practice)
      for (int i = 0; i < novf; ++i) {
        int d = ovf[2 * i + 1];
        int r = d - rbase;
        if (r >= 0 && r < 8) rstv[r] += feat[(size_t)ovf[2 * i] * DD + lane];
      }
    }

#pragma unroll
    for (int r = 0; r < 8; ++r) acc[r] = bv;

    float cur[8];
#pragma unroll
    for (int r = 0; r < 8; ++r)
      cur[r] = __uint_as_float(__builtin_amdgcn_readlane(__float_as_uint(rstv[r]), 0));
#pragma unroll
    for (int k = 0; k < 64; ++k) {
      float nxt[8];
      if (k < 63) {
#pragma unroll
        for (int r = 0; r < 8; ++r)
          nxt[r] = __uint_as_float(
              __builtin_amdgcn_readlane(__float_as_uint(rstv[r]), k + 1));
      }
#pragma unroll
      for (int r = 0; r < 8; ++r) acc[r] = fmaf(cur[r], w[k], acc[r]);
      if (k < 63) {
#pragma unroll
        for (int r = 0; r < 8; ++r) cur[r] = nxt[r];
      }
    }
#pragma unroll
    for (int r = 0; r < 8; ++r) out[(size_t)(rbase + r) * DD + lane] = acc[r];
  }
}

// row GEMM v3 (fallback paths only)
__global__ void __launch_bounds__(256) row_gemm3_kernel(float* __restrict__ out,
                                                        const float* __restrict__ W,
                                                        const float* __restrict__ b) {
  int lane = threadIdx.x & 63;
  int wid  = threadIdx.x >> 6;
  int g = blockIdx.x * 4 + wid;
  if (g >= NN / 16) return;
  int row0 = g * 16;

  float w[64];
#pragma unroll
  for (int k = 0; k < 64; ++k) w[k] = W[k * DD + lane];
  float bv = b[lane];

#pragma unroll
  for (int batch = 0; batch < 2; ++batch) {
    int rbase = row0 + batch * 8;
    float rstv[8], acc[8];
#pragma unroll
    for (int r = 0; r < 8; ++r) rstv[r] = out[(size_t)(rbase + r) * DD + lane];
#pragma unroll
    for (int r = 0; r < 8; ++r) acc[r] = bv;
#pragma unroll
    for (int k = 0; k < 64; ++k) {
#pragma unroll
      for (int r = 0; r < 8; ++r) {
        float s = __uint_as_float(__builtin_amdgcn_readlane(__float_as_uint(rstv[r]), k));
        acc[r] = fmaf(s, w[k], acc[r]);
      }
    }
#pragma unroll
    for (int r = 0; r < 8; ++r) out[(size_t)(rbase + r) * DD + lane] = acc[r];
  }
}

// ---------------- fallback path B: CSR pipeline ----------------

constexpr int NB_SCAN = (NN + 1023) / 1024;

__global__ void __launch_bounds__(256) zero_kernel(int* __restrict__ p, int n) {
  int i = blockIdx.x * blockDim.x + threadIdx.x;
  if (i < n) p[i] = 0;
}

__global__ void __launch_bounds__(256) hist_kernel(const int* __restrict__ dst,
                                                   int* __restrict__ count) {
  int e = blockIdx.x * blockDim.x + threadIdx.x;
  atomicAdd(&count[dst[e]], 1);
}

__global__ void __launch_bounds__(1024) scan1_kernel(const int* __restrict__ count,
                                                     int* __restrict__ offsets,
                                                     int* __restrict__ bsums) {
  __shared__ int tmp[1024];
  int tid = threadIdx.x;
  int gid = blockIdx.x * 1024 + tid;
  int v = (gid < NN) ? count[gid] : 0;
  tmp[tid] = v;
  __syncthreads();
  for (int off = 1; off < 1024; off <<= 1) {
    int t = (tid >= off) ? tmp[tid - off] : 0;
    __syncthreads();
    tmp[tid] += t;
    __syncthreads();
  }
  if (gid < NN) offsets[gid] = tmp[tid] - v;
  if (tid == 1023) bsums[blockIdx.x] = tmp[1023];
}

__global__ void __launch_bounds__(128) scan2_kernel(int* __restrict__ bsums) {
  __shared__ int tmp[128];
  int tid = threadIdx.x;
  int v = (tid < NB_SCAN) ? bsums[tid] : 0;
  tmp[tid] = v;
  __syncthreads();
  for (int off = 1; off < 128; off <<= 1) {
    int t = (tid >= off) ? tmp[tid - off] : 0;
    __syncthreads();
    tmp[tid] += t;
    __syncthreads();
  }
  if (tid < NB_SCAN) bsums[tid] = tmp[tid] - v;
}

__global__ void __launch_bounds__(256) scan3_kernel(int* __restrict__ offsets,
                                                    const int* __restrict__ bsums,
                                                    int* __restrict__ cursor) {
  int gid = blockIdx.x * blockDim.x + threadIdx.x;
  if (gid < NN) {
    int o = offsets[gid] + bsums[gid >> 10];
    offsets[gid] = o;
    cursor[gid] = o;
  } else if (gid == NN) {
    offsets[NN] = NE;
  }
}

__global__ void __launch_bounds__(256) place_kernel(const int* __restrict__ src,
                                                    const int* __restrict__ dst,
                                                    int* __restrict__ cursor,
                                                    int* __restrict__ sorted) {
  int e = blockIdx.x * blockDim.x + threadIdx.x;
  int p = atomicAdd(&cursor[dst[e]], 1);
  sorted[p] = src[e];
}

__global__ void __launch_bounds__(256) pull4_kernel(const float* __restrict__ feat,
                                                    const float* __restrict__ eps,
                                                    const int* __restrict__ offsets,
                                                    const int* __restrict__ sorted,
                                                    float* __restrict__ out) {
  int t = blockIdx.x * blockDim.x + threadIdx.x;
  int node = t >> 4;
  int q = t & 15;
  const float4* f4 = reinterpret_cast<const float4*>(feat);

  int start = offsets[node];
  int end   = offsets[node + 1];
  float e = 1.0f + eps[0];
  float4 self = f4[(size_t)node * 16 + q];
  float ax = e * self.x, ay = e * self.y, az = e * self.z, aw = e * self.w;

  int k = start;
  for (; k + 4 <= end; k += 4) {
    int s0 = sorted[k + 0], s1 = sorted[k + 1], s2 = sorted[k + 2], s3 = sorted[k + 3];
    float4 v0 = f4[(size_t)s0 * 16 + q];
    float4 v1 = f4[(size_t)s1 * 16 + q];
    float4 v2 = f4[(size_t)s2 * 16 + q];
    float4 v3 = f4[(size_t)s3 * 16 + q];
    ax += (v0.x + v1.x) + (v2.x + v3.x);
    ay += (v0.y + v1.y) + (v2.y + v3.y);
    az += (v0.z + v1.z) + (v2.z + v3.z);
    aw += (v0.w + v1.w) + (v2.w + v3.w);
  }
  for (; k < end; ++k) {
    int s = sorted[k];
    float4 v = f4[(size_t)s * 16 + q];
    ax += v.x; ay += v.y; az += v.z; aw += v.w;
  }

  reinterpret_cast<float4*>(out)[(size_t)node * 16 + q] = make_float4(ax, ay, az, aw);
}

// ---------------- fallback path C: atomic scatter ----------------

__global__ void __launch_bounds__(256) init_out_kernel(const float* __restrict__ feat,
                                                       const float* __restrict__ eps,
                                                       float* __restrict__ out) {
  int i = blockIdx.x * blockDim.x + threadIdx.x;
  float e = 1.0f + eps[0];
  float4 f = reinterpret_cast<const float4*>(feat)[i];
  reinterpret_cast<float4*>(out)[i] = make_float4(e * f.x, e * f.y, e * f.z, e * f.w);
}

__global__ void __launch_bounds__(256) scatter_edges_kernel(const float* __restrict__ feat,
                                                            const int* __restrict__ src,
                                                            const int* __restrict__ dst,
                                                            float* __restrict__ out) {
  int t = blockIdx.x * blockDim.x + threadIdx.x;
  int e = t >> 4;
  int q = t & 15;
  int s = src[e];
  int d = dst[e];
  float4 v = reinterpret_cast<const float4*>(feat)[s * 16 + q];
  float* op = out + d * DD + q * 4;
  atomicAdd(op + 0, v.x);
  atomicAdd(op + 1, v.y);
  atomicAdd(op + 2, v.z);
  atomicAdd(op + 3, v.w);
}

// ---------------- launch ----------------

extern "C" void kernel_launch(void* const* d_in, const int* in_sizes, int n_in,
                              void* d_out, int out_size, void* d_ws, size_t ws_size,
                              hipStream_t stream) {
  const float* feat = (const float*)d_in[0];
  const int* src    = (const int*)d_in[1];
  const int* dst    = (const int*)d_in[2];
  const float* eps  = (const float*)d_in[3];
  const float* W    = (const float*)d_in[4];
  const float* b    = (const float*)d_in[5];
  float* out        = (float*)d_out;

  // primary ws layout (ints): gcur[NBUCK] | ovf_cnt | pad | ovf[2*OVF_CAP] | sorted[NBUCK*CAP]
  const size_t needA = ((size_t)NBUCK + 2 + 2 * OVF_CAP + (size_t)NBUCK * CAP) * sizeof(int);
  // fallback B layout (ints): count[NN] | offsets[NN+1 pad 8] | cursor[NN] | bsums[128] | sorted[NE]
  const size_t needB = ((size_t)3 * NN + 136 + NE) * sizeof(int);

  if (ws_size >= needA) {
    int* wsI = (int*)d_ws;
    int* gcur    = wsI;
    int* ovf_cnt = wsI + NBUCK;
    int* ovf     = wsI + NBUCK + 2;
    unsigned int* sorted = (unsigned int*)(wsI + NBUCK + 2 + 2 * OVF_CAP);

    hipMemsetAsync(gcur, 0, (NBUCK + 2) * sizeof(int), stream);
    partition5_kernel<<<NPART, PTHREADS, 0, stream>>>(src, dst, gcur, ovf_cnt, ovf, sorted);
    bucket_agg2_kernel<<<NBUCK, 256, 0, stream>>>(feat, eps, gcur, sorted, out);
    row_gemm6_kernel<<<(NN / 16 + 3) / 4, 256, 0, stream>>>(out, W, b, ovf_cnt, ovf, feat);
  } else if (ws_size >= needB) {
    int* wsI     = (int*)d_ws;
    int* count   = wsI;
    int* offsets = wsI + NN;
    int* cursor  = wsI + 2 * NN + 8;
    int* bsums   = wsI + 3 * NN + 8;
    int* sortedB = wsI + 3 * NN + 136;

    zero_kernel<<<(NN + 255) / 256, 256, 0, stream>>>(count, NN);
    hist_kernel<<<NE / 256, 256, 0, stream>>>(dst, count);
    scan1_kernel<<<NB_SCAN, 1024, 0, stream>>>(count, offsets, bsums);
    scan2_kernel<<<1, 128, 0, stream>>>(bsums);
    scan3_kernel<<<(NN + 1 + 255) / 256, 256, 0, stream>>>(offsets, bsums, cursor);
    place_kernel<<<NE / 256, 256, 0, stream>>>(src, dst, cursor, sortedB);
    pull4_kernel<<<(NN * 16) / 256, 256, 0, stream>>>(feat, eps, offsets, sortedB, out);
    row_gemm3_kernel<<<(NN / 16 + 3) / 4, 256, 0, stream>>>(out, W, b);
  } else {
    init_out_kernel<<<(NN * DD / 4) / 256, 256, 0, stream>>>(feat, eps, out);
    scatter_edges_kernel<<<(NE * 16) / 256, 256, 0, stream>>>(feat, src, dst, out);
    row_gemm3_kernel<<<(NN / 16 + 3) / 4, 256, 0, stream>>>(out, W, b);
  }
}